// Round 1
// baseline (377.256 us; speedup 1.0000x reference)
//
#include <hip/hip_runtime.h>
#include <hip/hip_bf16.h>
#include <stdint.h>

#define NROW 4096
#define FDIM 512

typedef short bf16x8 __attribute__((ext_vector_type(8)));
typedef float f32x4 __attribute__((ext_vector_type(4)));

__device__ inline ushort f2bf(float f) {
    union { float f; uint32_t u; } c{f};
    uint32_t u = c.u;
    uint32_t r = (u + 0x7FFF + ((u >> 16) & 1)) >> 16;
    return (ushort)r;
}
__device__ inline float bf2f(ushort h) {
    union { uint32_t u; float f; } c{((uint32_t)h) << 16};
    return c.f;
}

__device__ inline float waveReduceMax(float v) {
    #pragma unroll
    for (int o = 32; o > 0; o >>= 1) v = fmaxf(v, __shfl_xor(v, o));
    return v;
}
__device__ inline float waveReduceSum(float v) {
    #pragma unroll
    for (int o = 32; o > 0; o >>= 1) v += __shfl_xor(v, o);
    return v;
}

#define GLL16(src, dst)                                                        \
    __builtin_amdgcn_global_load_lds(                                          \
        (const __attribute__((address_space(1))) void*)(src),                  \
        (__attribute__((address_space(3))) void*)(dst), 16, 0, 0)

// ---------------------------------------------------------------------------
// coef: softmax(alpha) and beta
__global__ __launch_bounds__(64) void coef_k(const float* __restrict__ alpha,
                                             const float* __restrict__ beta,
                                             float* __restrict__ coef) {
    if (threadIdx.x == 0) {
        float a0 = alpha[0], a1 = alpha[1], a2 = alpha[2];
        float m = fmaxf(a0, fmaxf(a1, a2));
        float e0 = expf(a0 - m), e1 = expf(a1 - m), e2 = expf(a2 - m);
        float s = e0 + e1 + e2;
        coef[0] = e0 / s; coef[1] = e1 / s; coef[2] = e2 / s;
        coef[3] = beta[0];
    }
}

// ---------------------------------------------------------------------------
// per-row normalize, produce xn hi/lo split (bf16x3) and bf16 x
__global__ __launch_bounds__(256) void prep_x(const float* __restrict__ x,
                                              ushort* __restrict__ xhi,
                                              ushort* __restrict__ xlo,
                                              ushort* __restrict__ xb) {
    int row = blockIdx.x, tid = threadIdx.x;
    int lane = tid & 63, w = tid >> 6;
    const float* xr = x + (size_t)row * FDIM;
    float v0 = xr[tid], v1 = xr[tid + 256];
    float ss = v0 * v0 + v1 * v1;
    ss = waveReduceSum(ss);
    __shared__ float b4[4];
    if (lane == 0) b4[w] = ss;
    __syncthreads();
    float tot = b4[0] + b4[1] + b4[2] + b4[3];
    float inv = 1.f / fmaxf(sqrtf(tot), 1e-12f);
    float n0 = v0 * inv, n1 = v1 * inv;
    ushort h0 = f2bf(n0), h1 = f2bf(n1);
    size_t o = (size_t)row * FDIM + tid;
    xhi[o] = h0;            xhi[o + 256] = h1;
    xlo[o] = f2bf(n0 - bf2f(h0));
    xlo[o + 256] = f2bf(n1 - bf2f(h1));
    xb[o] = f2bf(v0);       xb[o + 256] = f2bf(v1);
}

// ---------------------------------------------------------------------------
// transpose bf16 4096x512 -> 512x4096
__global__ __launch_bounds__(256) void transpose_xb(const ushort* __restrict__ in,
                                                    ushort* __restrict__ out) {
    __shared__ ushort t[64][65];
    int lx = threadIdx.x & 63, ly = threadIdx.x >> 6;
    int c0 = blockIdx.x * 64, r0 = blockIdx.y * 64;
    #pragma unroll
    for (int i = 0; i < 16; i++)
        t[ly + 4 * i][lx] = in[(size_t)(r0 + ly + 4 * i) * FDIM + c0 + lx];
    __syncthreads();
    #pragma unroll
    for (int i = 0; i < 16; i++)
        out[(size_t)(c0 + ly + 4 * i) * NROW + r0 + lx] = t[lx][ly + 4 * i];
}

// convert + transpose fp32 512x512 weight -> bf16 512x512 (transposed)
__global__ __launch_bounds__(256) void convT_w(const float* __restrict__ Wf,
                                               ushort* __restrict__ WT) {
    __shared__ ushort t[64][65];
    int lx = threadIdx.x & 63, ly = threadIdx.x >> 6;
    int c0 = blockIdx.x * 64, r0 = blockIdx.y * 64;
    #pragma unroll
    for (int i = 0; i < 16; i++)
        t[ly + 4 * i][lx] = f2bf(Wf[(size_t)(r0 + ly + 4 * i) * 512 + c0 + lx]);
    __syncthreads();
    #pragma unroll
    for (int i = 0; i < 16; i++)
        WT[(size_t)(c0 + ly + 4 * i) * 512 + r0 + lx] = t[lx][ly + 4 * i];
}

// ---------------------------------------------------------------------------
// Generic C = A(MxK) * B(NnxK)^T, bf16 MFMA 16x16x32, 128x128 tile, 4 waves.
// X3: split-precision (A=hi,A2=lo etc): acc += hi*hi + hi*lo + lo*hi.
// EPI 0: write fp32 C.  EPI 1: write fp32 C + bias[col].
// EPI 2: h = relu(cb*hlow + (1-cb)*acc) -> bf16 C.
template <int EPI, bool X3, int BK>
__global__ __launch_bounds__(256) void gemm_abT(
    const ushort* __restrict__ A, const ushort* __restrict__ A2, int lda,
    const ushort* __restrict__ B, const ushort* __restrict__ B2, int ldb,
    int Kdim, int ldc,
    float* __restrict__ Cf, ushort* __restrict__ Cb,
    const float* __restrict__ bias, const float* __restrict__ hlow,
    const float* __restrict__ coef) {
    constexpr int NT = 128 * BK;            // elems per tile
    constexpr int CPR = BK / 8;             // 16B chunks per row
    constexpr int PASSES = (128 * CPR) / 256;
    __shared__ __align__(16) ushort smem[(X3 ? 4 : 2) * NT];
    ushort* As = smem;
    ushort* Bs = smem + (X3 ? 2 : 1) * NT;

    const int tid = threadIdx.x;
    const int lane = tid & 63, w = tid >> 6;
    const int wr = w >> 1, wc = w & 1;
    const int m0 = blockIdx.y * 128;
    const int n0 = blockIdx.x * 128;

    f32x4 acc[4][4];
    #pragma unroll
    for (int mi = 0; mi < 4; mi++)
        #pragma unroll
        for (int ni = 0; ni < 4; ni++)
            #pragma unroll
            for (int r = 0; r < 4; r++) acc[mi][ni][r] = 0.f;

    for (int k0 = 0; k0 < Kdim; k0 += BK) {
        #pragma unroll
        for (int p = 0; p < PASSES; ++p) {
            int chunk = p * 256 + tid;
            int row = chunk / CPR;
            int kc = chunk % CPR;
            size_t go = (size_t)row * 0;  // placeholder to keep types clear
            (void)go;
            const ushort* asrc = A + (size_t)(m0 + row) * lda + k0 + kc * 8;
            const ushort* bsrc = B + (size_t)(n0 + row) * ldb + k0 + kc * 8;
            ushort* abase = As + (size_t)(p * 256 + w * 64) * 8;
            ushort* bbase = Bs + (size_t)(p * 256 + w * 64) * 8;
            GLL16(asrc, abase);
            GLL16(bsrc, bbase);
            if constexpr (X3) {
                const ushort* a2 = A2 + (size_t)(m0 + row) * lda + k0 + kc * 8;
                const ushort* b2 = B2 + (size_t)(n0 + row) * ldb + k0 + kc * 8;
                GLL16(a2, smem + NT + (size_t)(p * 256 + w * 64) * 8);
                GLL16(b2, smem + 3 * NT + (size_t)(p * 256 + w * 64) * 8);
            }
        }
        __syncthreads();
        #pragma unroll
        for (int kf = 0; kf < BK / 32; ++kf) {
            const int ko = kf * 32 + (lane >> 4) * 8;
            bf16x8 av[4], bv[4];
            #pragma unroll
            for (int mi = 0; mi < 4; mi++)
                av[mi] = *(const bf16x8*)&As[(wr * 64 + mi * 16 + (lane & 15)) * BK + ko];
            #pragma unroll
            for (int ni = 0; ni < 4; ni++)
                bv[ni] = *(const bf16x8*)&Bs[(wc * 64 + ni * 16 + (lane & 15)) * BK + ko];
            if constexpr (!X3) {
                #pragma unroll
                for (int mi = 0; mi < 4; mi++)
                    #pragma unroll
                    for (int ni = 0; ni < 4; ni++)
                        acc[mi][ni] = __builtin_amdgcn_mfma_f32_16x16x32_bf16(
                            av[mi], bv[ni], acc[mi][ni], 0, 0, 0);
            } else {
                bf16x8 av2[4], bv2[4];
                #pragma unroll
                for (int mi = 0; mi < 4; mi++)
                    av2[mi] = *(const bf16x8*)&smem[NT + (wr * 64 + mi * 16 + (lane & 15)) * BK + ko];
                #pragma unroll
                for (int ni = 0; ni < 4; ni++)
                    bv2[ni] = *(const bf16x8*)&smem[3 * NT + (wc * 64 + ni * 16 + (lane & 15)) * BK + ko];
                #pragma unroll
                for (int mi = 0; mi < 4; mi++)
                    #pragma unroll
                    for (int ni = 0; ni < 4; ni++) {
                        acc[mi][ni] = __builtin_amdgcn_mfma_f32_16x16x32_bf16(
                            av[mi], bv[ni], acc[mi][ni], 0, 0, 0);
                        acc[mi][ni] = __builtin_amdgcn_mfma_f32_16x16x32_bf16(
                            av[mi], bv2[ni], acc[mi][ni], 0, 0, 0);
                        acc[mi][ni] = __builtin_amdgcn_mfma_f32_16x16x32_bf16(
                            av2[mi], bv[ni], acc[mi][ni], 0, 0, 0);
                    }
            }
        }
        __syncthreads();
    }

    float cb = 0.f;
    if constexpr (EPI == 2) cb = coef[3];
    #pragma unroll
    for (int mi = 0; mi < 4; mi++) {
        #pragma unroll
        for (int ni = 0; ni < 4; ni++) {
            int col = n0 + wc * 64 + ni * 16 + (lane & 15);
            #pragma unroll
            for (int r = 0; r < 4; r++) {
                int rowg = m0 + wr * 64 + mi * 16 + (lane >> 4) * 4 + r;
                size_t off = (size_t)rowg * ldc + col;
                float v = acc[mi][ni][r];
                if constexpr (EPI == 0) {
                    Cf[off] = v;
                } else if constexpr (EPI == 1) {
                    Cf[off] = v + bias[col];
                } else {
                    float h = cb * hlow[off] + (1.f - cb) * v;
                    Cb[off] = f2bf(fmaxf(h, 0.f));
                }
            }
        }
    }
}

// ---------------------------------------------------------------------------
// Per row: top-8 threshold per hop over a_k*adj_k*sim, then
// M[row][j] = sim[row][j] * sum_k a_k^2 * adj_k[row][j] * mask_k[j]  (bf16)
__global__ __launch_bounds__(256) void topk_build_M(
    const float* __restrict__ sim, const float* __restrict__ adj,
    const float* __restrict__ rmask, const float* __restrict__ coef,
    ushort* __restrict__ Mout) {
    const int row = blockIdx.x;
    const int tid = threadIdx.x;
    const int lane = tid & 63, w = tid >> 6;
    __shared__ float ssim[NROW];
    __shared__ float b4[4];
    __shared__ int winner;
    const float* srow = sim + (size_t)row * NROW;
    for (int j = tid; j < NROW; j += 256) ssim[j] = srow[j];
    __syncthreads();

    float msum[16];
    #pragma unroll
    for (int i = 0; i < 16; i++) msum[i] = 0.f;

    for (int k = 0; k < 3; ++k) {
        const float ak = coef[k];
        const float* arow = adj + ((size_t)k * NROW + row) * NROW;
        const float* rrow = rmask + ((size_t)k * NROW + row) * NROW;
        float av[16];
        float loc[8];
        #pragma unroll
        for (int i = 0; i < 8; i++) loc[i] = -__builtin_inff();
        #pragma unroll 4
        for (int idx = 0; idx < 16; ++idx) {
            int j = tid + idx * 256;
            av[idx] = arow[j];
            float v = ak * av[idx] * ssim[j];
            if (v > loc[7]) {
                loc[7] = v;
                #pragma unroll
                for (int i = 7; i > 0; --i) {
                    if (loc[i] > loc[i - 1]) {
                        float t = loc[i - 1]; loc[i - 1] = loc[i]; loc[i] = t;
                    }
                }
            }
        }
        // extract global 8th-largest across the block
        int ptr = 0;
        float thrk = 0.f;
        for (int it = 0; it < 8; ++it) {
            float cand = (ptr < 8) ? loc[ptr] : -__builtin_inff();
            float wm = waveReduceMax(cand);
            if (lane == 0) b4[w] = wm;
            __syncthreads();
            float mx = fmaxf(fmaxf(b4[0], b4[1]), fmaxf(b4[2], b4[3]));
            if (ptr < 8 && cand == mx) winner = tid;
            __syncthreads();
            if (tid == winner) ptr++;
            thrk = mx;
            __syncthreads();
        }
        const float aksq = ak * ak;
        #pragma unroll 4
        for (int idx = 0; idx < 16; ++idx) {
            int j = tid + idx * 256;
            float v = ak * av[idx] * ssim[j];
            bool m = (rrow[j] < 0.5f) || (v >= thrk);
            msum[idx] += m ? aksq * av[idx] : 0.f;
        }
    }
    ushort* mrow = Mout + (size_t)row * NROW;
    #pragma unroll 4
    for (int idx = 0; idx < 16; ++idx) {
        int j = tid + idx * 256;
        mrow[j] = f2bf(ssim[j] * msum[idx]);
    }
}

// ---------------------------------------------------------------------------
__global__ __launch_bounds__(256) void logsoftmax_k(const float* __restrict__ L,
                                                    float* __restrict__ out) {
    int row = blockIdx.x, tid = threadIdx.x;
    int lane = tid & 63, w = tid >> 6;
    const float* lr = L + (size_t)row * 512;
    float v0 = lr[tid], v1 = lr[tid + 256];
    __shared__ float bm[4], bs[4];
    float m = fmaxf(v0, v1);
    m = waveReduceMax(m);
    if (lane == 0) bm[w] = m;
    __syncthreads();
    float M = fmaxf(fmaxf(bm[0], bm[1]), fmaxf(bm[2], bm[3]));
    float s = expf(v0 - M) + expf(v1 - M);
    s = waveReduceSum(s);
    if (lane == 0) bs[w] = s;
    __syncthreads();
    float S = bs[0] + bs[1] + bs[2] + bs[3];
    float lse = M + logf(S);
    float* orow = out + (size_t)row * 512;
    orow[tid] = v0 - lse;
    orow[tid + 256] = v1 - lse;
}

// ---------------------------------------------------------------------------
extern "C" void kernel_launch(void* const* d_in, const int* in_sizes, int n_in,
                              void* d_out, int out_size, void* d_ws, size_t ws_size,
                              hipStream_t stream) {
    const float* x     = (const float*)d_in[0];
    const float* adj   = (const float*)d_in[1];
    const float* rmask = (const float*)d_in[2];
    const float* W_in  = (const float*)d_in[3];
    const float* b_in  = (const float*)d_in[4];
    const float* W_out = (const float*)d_in[5];
    const float* b_out = (const float*)d_in[6];
    const float* alpha = (const float*)d_in[7];
    const float* beta  = (const float*)d_in[8];
    float* out = (float*)d_out;

    const size_t MB = 1024 * 1024;
    char* wsb = (char*)d_ws;
    float*  sim    = (float*)wsb;                  // 64 MB, dead after topk
    ushort* Mb     = (ushort*)(wsb + 64 * MB);     // 32 MB
    ushort* xhi    = (ushort*)(wsb + 96 * MB);     // 4 MB
    ushort* xlo    = (ushort*)(wsb + 100 * MB);    // 4 MB
    ushort* xb     = (ushort*)(wsb + 104 * MB);    // 4 MB
    ushort* xbT    = (ushort*)(wsb + 108 * MB);    // 4 MB
    ushort* WinT   = (ushort*)(wsb + 112 * MB);    // 0.5 MB
    ushort* WoutT  = (ushort*)(wsb + 113 * MB);    // 0.5 MB
    float*  coef   = (float*)(wsb + 114 * MB);     // 16 B
    // aliases into the (dead) sim region:
    float*  Hlow   = (float*)wsb;                  // 8 MB
    ushort* Hb     = (ushort*)(wsb + 8 * MB);      // 4 MB
    float*  logits = (float*)(wsb + 12 * MB);      // 8 MB

    coef_k<<<1, 64, 0, stream>>>(alpha, beta, coef);
    prep_x<<<NROW, 256, 0, stream>>>(x, xhi, xlo, xb);
    transpose_xb<<<dim3(8, 64), 256, 0, stream>>>(xb, xbT);
    convT_w<<<dim3(8, 8), 256, 0, stream>>>(W_in, WinT);
    convT_w<<<dim3(8, 8), 256, 0, stream>>>(W_out, WoutT);

    // sim = xn @ xn^T  (bf16x3 split precision)
    gemm_abT<0, true, 32><<<dim3(32, 32), 256, 0, stream>>>(
        xhi, xlo, FDIM, xhi, xlo, FDIM, FDIM, NROW,
        sim, nullptr, nullptr, nullptr, nullptr);

    // combined masked adjacency M (bf16)
    topk_build_M<<<NROW, 256, 0, stream>>>(sim, adj, rmask, coef, Mb);

    // H_low = x @ W_in + b_in   (into dead sim region)
    gemm_abT<1, false, 64><<<dim3(4, 32), 256, 0, stream>>>(
        xb, nullptr, FDIM, WinT, nullptr, FDIM, FDIM, 512,
        Hlow, nullptr, b_in, nullptr, nullptr);

    // H = relu(b*H_low + (1-b)*(M @ x))  -> bf16
    gemm_abT<2, false, 64><<<dim3(4, 32), 256, 0, stream>>>(
        Mb, nullptr, NROW, xbT, nullptr, NROW, NROW, 512,
        nullptr, Hb, nullptr, Hlow, coef);

    // logits = H @ W_out + b_out
    gemm_abT<1, false, 64><<<dim3(4, 32), 256, 0, stream>>>(
        Hb, nullptr, 512, WoutT, nullptr, 512, 512, 512,
        logits, nullptr, b_out, nullptr, nullptr);

    logsoftmax_k<<<NROW, 256, 0, stream>>>(logits, out);
}

// Round 2
// 335.747 us; speedup vs baseline: 1.1236x; 1.1236x over previous
//
#include <hip/hip_runtime.h>
#include <hip/hip_bf16.h>
#include <stdint.h>

#define NROW 4096
#define FDIM 512

typedef short bf16x8 __attribute__((ext_vector_type(8)));
typedef float f32x4 __attribute__((ext_vector_type(4)));
typedef float f4 __attribute__((ext_vector_type(4)));
typedef ushort u16x4 __attribute__((ext_vector_type(4)));

#define NEG_INF (-__builtin_inff())

__device__ inline ushort f2bf(float f) {
    union { float f; uint32_t u; } c{f};
    uint32_t u = c.u;
    uint32_t r = (u + 0x7FFF + ((u >> 16) & 1)) >> 16;
    return (ushort)r;
}
__device__ inline float bf2f(ushort h) {
    union { uint32_t u; float f; } c{((uint32_t)h) << 16};
    return c.f;
}

__device__ inline float waveReduceMax(float v) {
    #pragma unroll
    for (int o = 32; o > 0; o >>= 1) v = fmaxf(v, __shfl_xor(v, o));
    return v;
}
__device__ inline float waveReduceSum(float v) {
    #pragma unroll
    for (int o = 32; o > 0; o >>= 1) v += __shfl_xor(v, o);
    return v;
}

#define GLL16(src, dst)                                                        \
    __builtin_amdgcn_global_load_lds(                                          \
        (const __attribute__((address_space(1))) void*)(src),                  \
        (__attribute__((address_space(3))) void*)(dst), 16, 0, 0)

// ---------------------------------------------------------------------------
__global__ __launch_bounds__(64) void coef_k(const float* __restrict__ alpha,
                                             const float* __restrict__ beta,
                                             float* __restrict__ coef) {
    if (threadIdx.x == 0) {
        float a0 = alpha[0], a1 = alpha[1], a2 = alpha[2];
        float m = fmaxf(a0, fmaxf(a1, a2));
        float e0 = expf(a0 - m), e1 = expf(a1 - m), e2 = expf(a2 - m);
        float s = e0 + e1 + e2;
        coef[0] = e0 / s; coef[1] = e1 / s; coef[2] = e2 / s;
        coef[3] = beta[0];
    }
}

// ---------------------------------------------------------------------------
__global__ __launch_bounds__(256) void prep_x(const float* __restrict__ x,
                                              ushort* __restrict__ xhi,
                                              ushort* __restrict__ xlo,
                                              ushort* __restrict__ xb) {
    int row = blockIdx.x, tid = threadIdx.x;
    int lane = tid & 63, w = tid >> 6;
    const float* xr = x + (size_t)row * FDIM;
    float v0 = xr[tid], v1 = xr[tid + 256];
    float ss = v0 * v0 + v1 * v1;
    ss = waveReduceSum(ss);
    __shared__ float b4[4];
    if (lane == 0) b4[w] = ss;
    __syncthreads();
    float tot = b4[0] + b4[1] + b4[2] + b4[3];
    float inv = 1.f / fmaxf(sqrtf(tot), 1e-12f);
    float n0 = v0 * inv, n1 = v1 * inv;
    ushort h0 = f2bf(n0), h1 = f2bf(n1);
    size_t o = (size_t)row * FDIM + tid;
    xhi[o] = h0;            xhi[o + 256] = h1;
    xlo[o] = f2bf(n0 - bf2f(h0));
    xlo[o + 256] = f2bf(n1 - bf2f(h1));
    xb[o] = f2bf(v0);       xb[o + 256] = f2bf(v1);
}

// ---------------------------------------------------------------------------
__global__ __launch_bounds__(256) void transpose_xb(const ushort* __restrict__ in,
                                                    ushort* __restrict__ out) {
    __shared__ ushort t[64][65];
    int lx = threadIdx.x & 63, ly = threadIdx.x >> 6;
    int c0 = blockIdx.x * 64, r0 = blockIdx.y * 64;
    #pragma unroll
    for (int i = 0; i < 16; i++)
        t[ly + 4 * i][lx] = in[(size_t)(r0 + ly + 4 * i) * FDIM + c0 + lx];
    __syncthreads();
    #pragma unroll
    for (int i = 0; i < 16; i++)
        out[(size_t)(c0 + ly + 4 * i) * NROW + r0 + lx] = t[lx][ly + 4 * i];
}

__global__ __launch_bounds__(256) void convT_w(const float* __restrict__ Wf,
                                               ushort* __restrict__ WT) {
    __shared__ ushort t[64][65];
    int lx = threadIdx.x & 63, ly = threadIdx.x >> 6;
    int c0 = blockIdx.x * 64, r0 = blockIdx.y * 64;
    #pragma unroll
    for (int i = 0; i < 16; i++)
        t[ly + 4 * i][lx] = f2bf(Wf[(size_t)(r0 + ly + 4 * i) * 512 + c0 + lx]);
    __syncthreads();
    #pragma unroll
    for (int i = 0; i < 16; i++)
        WT[(size_t)(c0 + ly + 4 * i) * 512 + r0 + lx] = t[lx][ly + 4 * i];
}

// ---------------------------------------------------------------------------
// Generic C = A(MxK) * B(NnxK)^T, bf16 MFMA 16x16x32, 128x128 tile, 4 waves.
// X3: split-precision: acc += hi*hi + hi*lo + lo*hi.
// EPI 0: fp32 C.  EPI 1: fp32 C + bias[col].  EPI 3: split-K partial fp32
// (blockIdx.z selects K-chunk of 512, writes to its own 8MB slab).
template <int EPI, bool X3, int BK>
__global__ __launch_bounds__(256) void gemm_abT(
    const ushort* __restrict__ A, const ushort* __restrict__ A2, int lda,
    const ushort* __restrict__ B, const ushort* __restrict__ B2, int ldb,
    int Kdim, int ldc,
    float* __restrict__ Cf, ushort* __restrict__ Cb,
    const float* __restrict__ bias, const float* __restrict__ hlow,
    const float* __restrict__ coef) {
    constexpr int NT = 128 * BK;
    constexpr int CPR = BK / 8;
    constexpr int PASSES = (128 * CPR) / 256;
    __shared__ __align__(16) ushort smem[(X3 ? 4 : 2) * NT];
    ushort* As = smem;
    ushort* Bs = smem + (X3 ? 2 : 1) * NT;

    if constexpr (EPI == 3) {
        A += (size_t)blockIdx.z * 512;
        B += (size_t)blockIdx.z * 512;
        Cf += (size_t)blockIdx.z * ((size_t)NROW * 512);
    }

    const int tid = threadIdx.x;
    const int lane = tid & 63, w = tid >> 6;
    const int wr = w >> 1, wc = w & 1;
    const int m0 = blockIdx.y * 128;
    const int n0 = blockIdx.x * 128;

    f32x4 acc[4][4];
    #pragma unroll
    for (int mi = 0; mi < 4; mi++)
        #pragma unroll
        for (int ni = 0; ni < 4; ni++)
            #pragma unroll
            for (int r = 0; r < 4; r++) acc[mi][ni][r] = 0.f;

    for (int k0 = 0; k0 < Kdim; k0 += BK) {
        #pragma unroll
        for (int p = 0; p < PASSES; ++p) {
            int chunk = p * 256 + tid;
            int row = chunk / CPR;
            int kc = chunk % CPR;
            const ushort* asrc = A + (size_t)(m0 + row) * lda + k0 + kc * 8;
            const ushort* bsrc = B + (size_t)(n0 + row) * ldb + k0 + kc * 8;
            ushort* abase = As + (size_t)(p * 256 + w * 64) * 8;
            ushort* bbase = Bs + (size_t)(p * 256 + w * 64) * 8;
            GLL16(asrc, abase);
            GLL16(bsrc, bbase);
            if constexpr (X3) {
                const ushort* a2 = A2 + (size_t)(m0 + row) * lda + k0 + kc * 8;
                const ushort* b2 = B2 + (size_t)(n0 + row) * ldb + k0 + kc * 8;
                GLL16(a2, smem + NT + (size_t)(p * 256 + w * 64) * 8);
                GLL16(b2, smem + 3 * NT + (size_t)(p * 256 + w * 64) * 8);
            }
        }
        __syncthreads();
        #pragma unroll
        for (int kf = 0; kf < BK / 32; ++kf) {
            const int ko = kf * 32 + (lane >> 4) * 8;
            bf16x8 av[4], bv[4];
            #pragma unroll
            for (int mi = 0; mi < 4; mi++)
                av[mi] = *(const bf16x8*)&As[(wr * 64 + mi * 16 + (lane & 15)) * BK + ko];
            #pragma unroll
            for (int ni = 0; ni < 4; ni++)
                bv[ni] = *(const bf16x8*)&Bs[(wc * 64 + ni * 16 + (lane & 15)) * BK + ko];
            if constexpr (!X3) {
                #pragma unroll
                for (int mi = 0; mi < 4; mi++)
                    #pragma unroll
                    for (int ni = 0; ni < 4; ni++)
                        acc[mi][ni] = __builtin_amdgcn_mfma_f32_16x16x32_bf16(
                            av[mi], bv[ni], acc[mi][ni], 0, 0, 0);
            } else {
                bf16x8 av2[4], bv2[4];
                #pragma unroll
                for (int mi = 0; mi < 4; mi++)
                    av2[mi] = *(const bf16x8*)&smem[NT + (wr * 64 + mi * 16 + (lane & 15)) * BK + ko];
                #pragma unroll
                for (int ni = 0; ni < 4; ni++)
                    bv2[ni] = *(const bf16x8*)&smem[3 * NT + (wc * 64 + ni * 16 + (lane & 15)) * BK + ko];
                #pragma unroll
                for (int mi = 0; mi < 4; mi++)
                    #pragma unroll
                    for (int ni = 0; ni < 4; ni++) {
                        acc[mi][ni] = __builtin_amdgcn_mfma_f32_16x16x32_bf16(
                            av[mi], bv[ni], acc[mi][ni], 0, 0, 0);
                        acc[mi][ni] = __builtin_amdgcn_mfma_f32_16x16x32_bf16(
                            av[mi], bv2[ni], acc[mi][ni], 0, 0, 0);
                        acc[mi][ni] = __builtin_amdgcn_mfma_f32_16x16x32_bf16(
                            av2[mi], bv[ni], acc[mi][ni], 0, 0, 0);
                    }
            }
        }
        __syncthreads();
    }

    #pragma unroll
    for (int mi = 0; mi < 4; mi++) {
        #pragma unroll
        for (int ni = 0; ni < 4; ni++) {
            int col = n0 + wc * 64 + ni * 16 + (lane & 15);
            #pragma unroll
            for (int r = 0; r < 4; r++) {
                int rowg = m0 + wr * 64 + mi * 16 + (lane >> 4) * 4 + r;
                size_t off = (size_t)rowg * ldc + col;
                float v = acc[mi][ni][r];
                if constexpr (EPI == 0 || EPI == 3) {
                    Cf[off] = v;
                } else if constexpr (EPI == 1) {
                    Cf[off] = v + bias[col];
                }
            }
        }
    }
}

// ---------------------------------------------------------------------------
// topk + build M. One block per row, 256 threads; thread owns 16 contiguous
// cols: j = q*1024 + tid*4 + c (q<4, c<4). sim row lives in registers across
// the 3 hops. Exact 8th-largest of adj*sim per hop via:
//   per-thread sorted top-8 -> per-wave 8-round shuffle knockout (no barrier)
//   -> 1 barrier -> 32-candidate lane knockout.
__global__ __launch_bounds__(256) void topk_build_M(
    const float* __restrict__ sim, const float* __restrict__ adj,
    const float* __restrict__ rmask, const float* __restrict__ coef,
    ushort* __restrict__ Mout) {
    const int row = blockIdx.x;
    const int tid = threadIdx.x;
    const int lane = tid & 63, w = tid >> 6;
    __shared__ float wl[3 * 32];

    const f4* srow4 = (const f4*)(sim + (size_t)row * NROW);
    f4 sv[4];
    #pragma unroll
    for (int q = 0; q < 4; q++) sv[q] = srow4[q * 256 + tid];

    f4 msum[4];
    #pragma unroll
    for (int q = 0; q < 4; q++)
        #pragma unroll
        for (int c = 0; c < 4; c++) msum[q][c] = 0.f;

    for (int k = 0; k < 3; ++k) {
        const f4* arow4 = (const f4*)(adj + ((size_t)k * NROW + row) * NROW);
        const f4* rrow4 = (const f4*)(rmask + ((size_t)k * NROW + row) * NROW);
        f4 av[4], rv[4];
        #pragma unroll
        for (int q = 0; q < 4; q++) av[q] = arow4[q * 256 + tid];
        #pragma unroll
        for (int q = 0; q < 4; q++) rv[q] = rrow4[q * 256 + tid];

        uint32_t rbits = 0;
        #pragma unroll
        for (int q = 0; q < 4; q++)
            #pragma unroll
            for (int c = 0; c < 4; c++)
                rbits |= (rv[q][c] < 0.5f) ? (1u << (q * 4 + c)) : 0u;

        // per-thread sorted (desc) top-8 of v = adj*sim
        float l[8];
        #pragma unroll
        for (int i = 0; i < 8; i++) l[i] = NEG_INF;
        #pragma unroll
        for (int q = 0; q < 4; q++) {
            #pragma unroll
            for (int c = 0; c < 4; c++) {
                float v = av[q][c] * sv[q][c];
                if (v > l[7]) {
                    l[7] = v;
                    #pragma unroll
                    for (int i = 7; i > 0; --i) {
                        if (l[i] > l[i - 1]) { float t = l[i - 1]; l[i - 1] = l[i]; l[i] = t; }
                    }
                }
            }
        }

        // per-wave knockout: 8 rounds, heads only; winner shifts its list
        #pragma unroll
        for (int rr = 0; rr < 8; rr++) {
            float m = waveReduceMax(l[0]);
            if (lane == 0) wl[k * 32 + w * 8 + rr] = m;
            unsigned long long mk = __ballot(l[0] == m);
            if (lane == __ffsll(mk) - 1) {
                #pragma unroll
                for (int i = 0; i < 7; i++) l[i] = l[i + 1];
                l[7] = NEG_INF;
            }
        }
        __syncthreads();

        // 8th-largest of the 32 wave-candidates (each wave redundantly)
        float xv = (lane < 32) ? wl[k * 32 + lane] : NEG_INF;
        float thr = NEG_INF;
        #pragma unroll
        for (int rr = 0; rr < 8; rr++) {
            float m = waveReduceMax(xv);
            thr = m;
            unsigned long long mk = __ballot(xv == m);
            if (lane == __ffsll(mk) - 1) xv = NEG_INF;
        }

        const float ak = coef[k];
        const float aksq = ak * ak;
        #pragma unroll
        for (int q = 0; q < 4; q++) {
            #pragma unroll
            for (int c = 0; c < 4; c++) {
                float v = av[q][c] * sv[q][c];
                bool m = ((rbits >> (q * 4 + c)) & 1) || (v >= thr);
                msum[q][c] += m ? aksq * av[q][c] : 0.f;
            }
        }
    }

    ushort* mrow = Mout + (size_t)row * NROW;
    #pragma unroll
    for (int q = 0; q < 4; q++) {
        u16x4 o;
        #pragma unroll
        for (int c = 0; c < 4; c++) o[c] = f2bf(sv[q][c] * msum[q][c]);
        *(u16x4*)(mrow + q * 1024 + tid * 4) = o;
    }
}

// ---------------------------------------------------------------------------
// H = relu(cb*Hlow + (1-cb)*sum_z parts[z]) -> bf16
__global__ __launch_bounds__(256) void reduce_relu(
    const float* __restrict__ parts, const float* __restrict__ hlow,
    const float* __restrict__ coef, ushort* __restrict__ Hb) {
    const size_t i = (size_t)blockIdx.x * 256 + threadIdx.x;  // f4 index
    const f4* p4 = (const f4*)parts;
    f4 s = p4[i];
    #pragma unroll
    for (int z = 1; z < 8; z++) s += p4[(size_t)z * 524288 + i];
    f4 hl = ((const f4*)hlow)[i];
    float cb = coef[3];
    u16x4 o;
    #pragma unroll
    for (int c = 0; c < 4; c++) {
        float h = cb * hl[c] + (1.f - cb) * s[c];
        o[c] = f2bf(fmaxf(h, 0.f));
    }
    *((u16x4*)Hb + i) = o;
}

// ---------------------------------------------------------------------------
__global__ __launch_bounds__(256) void logsoftmax_k(const float* __restrict__ L,
                                                    float* __restrict__ out) {
    int row = blockIdx.x, tid = threadIdx.x;
    int lane = tid & 63, w = tid >> 6;
    const float* lr = L + (size_t)row * 512;
    float v0 = lr[tid], v1 = lr[tid + 256];
    __shared__ float bm[4], bs[4];
    float m = fmaxf(v0, v1);
    m = waveReduceMax(m);
    if (lane == 0) bm[w] = m;
    __syncthreads();
    float M = fmaxf(fmaxf(bm[0], bm[1]), fmaxf(bm[2], bm[3]));
    float s = expf(v0 - M) + expf(v1 - M);
    s = waveReduceSum(s);
    if (lane == 0) bs[w] = s;
    __syncthreads();
    float S = bs[0] + bs[1] + bs[2] + bs[3];
    float lse = M + logf(S);
    float* orow = out + (size_t)row * 512;
    orow[tid] = v0 - lse;
    orow[tid + 256] = v1 - lse;
}

// ---------------------------------------------------------------------------
extern "C" void kernel_launch(void* const* d_in, const int* in_sizes, int n_in,
                              void* d_out, int out_size, void* d_ws, size_t ws_size,
                              hipStream_t stream) {
    const float* x     = (const float*)d_in[0];
    const float* adj   = (const float*)d_in[1];
    const float* rmask = (const float*)d_in[2];
    const float* W_in  = (const float*)d_in[3];
    const float* b_in  = (const float*)d_in[4];
    const float* W_out = (const float*)d_in[5];
    const float* b_out = (const float*)d_in[6];
    const float* alpha = (const float*)d_in[7];
    const float* beta  = (const float*)d_in[8];
    float* out = (float*)d_out;

    const size_t MB = 1024 * 1024;
    char* wsb = (char*)d_ws;
    // [0,64)   : sim fp32 (dead after topk) -> then 8x8MB split-K parts -> then logits
    // [64,96)  : M bf16
    // [96,100) : xhi (dead after sim GEMM) -\
    // [100,104): xlo (dead after sim GEMM) --> Hlow fp32 [96,104)
    // [104,108): xb  (dead after Hlow GEMM) -> Hb bf16
    // [108,112): xbT
    // [112,113): WinT   [113,113.5): WoutT   [113.5): coef
    float*  sim    = (float*)wsb;
    float*  parts  = (float*)wsb;
    float*  logits = (float*)wsb;
    ushort* Mb     = (ushort*)(wsb + 64 * MB);
    ushort* xhi    = (ushort*)(wsb + 96 * MB);
    ushort* xlo    = (ushort*)(wsb + 100 * MB);
    float*  Hlow   = (float*)(wsb + 96 * MB);
    ushort* xb     = (ushort*)(wsb + 104 * MB);
    ushort* Hb     = (ushort*)(wsb + 104 * MB);
    ushort* xbT    = (ushort*)(wsb + 108 * MB);
    ushort* WinT   = (ushort*)(wsb + 112 * MB);
    ushort* WoutT  = (ushort*)(wsb + 113 * MB);
    float*  coef   = (float*)(wsb + 113 * MB + 512 * 1024);

    coef_k<<<1, 64, 0, stream>>>(alpha, beta, coef);
    prep_x<<<NROW, 256, 0, stream>>>(x, xhi, xlo, xb);
    transpose_xb<<<dim3(8, 64), 256, 0, stream>>>(xb, xbT);
    convT_w<<<dim3(8, 8), 256, 0, stream>>>(W_in, WinT);
    convT_w<<<dim3(8, 8), 256, 0, stream>>>(W_out, WoutT);

    // sim = xn @ xn^T  (bf16x3 split precision)
    gemm_abT<0, true, 32><<<dim3(32, 32), 256, 0, stream>>>(
        xhi, xlo, FDIM, xhi, xlo, FDIM, FDIM, NROW,
        sim, nullptr, nullptr, nullptr, nullptr);

    // combined masked adjacency M (bf16)
    topk_build_M<<<NROW, 256, 0, stream>>>(sim, adj, rmask, coef, Mb);

    // H_low = x @ W_in + b_in  (into dead xhi/xlo region)
    gemm_abT<1, false, 64><<<dim3(4, 32), 256, 0, stream>>>(
        xb, nullptr, FDIM, WinT, nullptr, FDIM, FDIM, 512,
        Hlow, nullptr, b_in, nullptr, nullptr);

    // split-K: parts[z] = M[:, z*512:(z+1)*512] @ x[z*512:(z+1)*512, :]
    gemm_abT<3, false, 64><<<dim3(4, 32, 8), 256, 0, stream>>>(
        Mb, nullptr, NROW, xbT, nullptr, NROW, 512, 512,
        parts, nullptr, nullptr, nullptr, nullptr);

    // H = relu(b*Hlow + (1-b)*sum parts) -> bf16 (into dead xb region)
    reduce_relu<<<2048, 256, 0, stream>>>(parts, Hlow, coef, Hb);

    // logits = H @ W_out + b_out  (into dead parts region)
    gemm_abT<1, false, 64><<<dim3(4, 32), 256, 0, stream>>>(
        Hb, nullptr, 512, WoutT, nullptr, 512, 512, 512,
        logits, nullptr, b_out, nullptr, nullptr);

    logsoftmax_k<<<NROW, 256, 0, stream>>>(logits, out);
}

// Round 3
// 217.056 us; speedup vs baseline: 1.7381x; 1.5468x over previous
//
#include <hip/hip_runtime.h>
#include <hip/hip_bf16.h>
#include <stdint.h>

#define NROW 4096
#define FDIM 512

typedef short bf16x8 __attribute__((ext_vector_type(8)));
typedef float f32x4 __attribute__((ext_vector_type(4)));
typedef float f4 __attribute__((ext_vector_type(4)));
typedef ushort u16x4 __attribute__((ext_vector_type(4)));

#define NEG_INF (-__builtin_inff())

__device__ inline ushort f2bf(float f) {
    union { float f; uint32_t u; } c{f};
    uint32_t u = c.u;
    uint32_t r = (u + 0x7FFF + ((u >> 16) & 1)) >> 16;
    return (ushort)r;
}
__device__ inline float bf2f(ushort h) {
    union { uint32_t u; float f; } c{((uint32_t)h) << 16};
    return c.f;
}
// packed bf16 pair helpers: lo = element 0, hi = element 1
__device__ inline uint32_t cvt_pk_bf16(float lo, float hi) {
    uint32_t r;
    asm("v_cvt_pk_bf16_f32 %0, %1, %2" : "=v"(r) : "v"(lo), "v"(hi));
    return r;
}
__device__ inline float up0(uint32_t p) {
    union { uint32_t u; float f; } c{p << 16}; return c.f;
}
__device__ inline float up1(uint32_t p) {
    union { uint32_t u; float f; } c{p & 0xFFFF0000u}; return c.f;
}

__device__ inline float waveReduceMax(float v) {
    #pragma unroll
    for (int o = 32; o > 0; o >>= 1) v = fmaxf(v, __shfl_xor(v, o));
    return v;
}
__device__ inline float waveReduceSum(float v) {
    #pragma unroll
    for (int o = 32; o > 0; o >>= 1) v += __shfl_xor(v, o);
    return v;
}

// ---- sorting-network primitives (descending) -------------------------------
__device__ inline void CE(float& a, float& b) {
    float mx = fmaxf(a, b);
    b = fminf(a, b);
    a = mx;
}
// Batcher odd-even mergesort, 8 elements, descending, 19 comparators
__device__ inline void sort8(float (&l)[8]) {
    CE(l[0],l[1]); CE(l[2],l[3]); CE(l[4],l[5]); CE(l[6],l[7]);
    CE(l[0],l[2]); CE(l[1],l[3]); CE(l[4],l[6]); CE(l[5],l[7]);
    CE(l[1],l[2]); CE(l[5],l[6]);
    CE(l[0],l[4]); CE(l[1],l[5]); CE(l[2],l[6]); CE(l[3],l[7]);
    CE(l[2],l[4]); CE(l[3],l[5]);
    CE(l[1],l[2]); CE(l[3],l[4]); CE(l[5],l[6]);
}
// a, b sorted desc -> a = sorted desc top-8 of union (bitonic half-merge)
__device__ inline void mergeTop8(float (&a)[8], const float (&b)[8]) {
    float t[8];
    #pragma unroll
    for (int i = 0; i < 8; i++) t[i] = fmaxf(a[i], b[7 - i]);
    CE(t[0],t[4]); CE(t[1],t[5]); CE(t[2],t[6]); CE(t[3],t[7]);
    CE(t[0],t[2]); CE(t[1],t[3]); CE(t[4],t[6]); CE(t[5],t[7]);
    CE(t[0],t[1]); CE(t[2],t[3]); CE(t[4],t[5]); CE(t[6],t[7]);
    #pragma unroll
    for (int i = 0; i < 8; i++) a[i] = t[i];
}

#define GLL16(src, dst)                                                        \
    __builtin_amdgcn_global_load_lds(                                          \
        (const __attribute__((address_space(1))) void*)(src),                  \
        (__attribute__((address_space(3))) void*)(dst), 16, 0, 0)

// ---------------------------------------------------------------------------
__global__ __launch_bounds__(64) void coef_k(const float* __restrict__ alpha,
                                             const float* __restrict__ beta,
                                             float* __restrict__ coef) {
    if (threadIdx.x == 0) {
        float a0 = alpha[0], a1 = alpha[1], a2 = alpha[2];
        float m = fmaxf(a0, fmaxf(a1, a2));
        float e0 = expf(a0 - m), e1 = expf(a1 - m), e2 = expf(a2 - m);
        float s = e0 + e1 + e2;
        coef[0] = e0 / s; coef[1] = e1 / s; coef[2] = e2 / s;
        coef[3] = beta[0];
    }
}

// ---------------------------------------------------------------------------
// per-row normalize -> xn bf16; raw cast -> xb bf16
__global__ __launch_bounds__(256) void prep_x(const float* __restrict__ x,
                                              ushort* __restrict__ xn,
                                              ushort* __restrict__ xb) {
    int row = blockIdx.x, tid = threadIdx.x;
    int lane = tid & 63, w = tid >> 6;
    const float* xr = x + (size_t)row * FDIM;
    float v0 = xr[tid], v1 = xr[tid + 256];
    float ss = v0 * v0 + v1 * v1;
    ss = waveReduceSum(ss);
    __shared__ float b4[4];
    if (lane == 0) b4[w] = ss;
    __syncthreads();
    float tot = b4[0] + b4[1] + b4[2] + b4[3];
    float inv = 1.f / fmaxf(sqrtf(tot), 1e-12f);
    size_t o = (size_t)row * FDIM + tid;
    xn[o] = f2bf(v0 * inv);  xn[o + 256] = f2bf(v1 * inv);
    xb[o] = f2bf(v0);        xb[o + 256] = f2bf(v1);
}

// ---------------------------------------------------------------------------
__global__ __launch_bounds__(256) void transpose_xb(const ushort* __restrict__ in,
                                                    ushort* __restrict__ out) {
    __shared__ ushort t[64][65];
    int lx = threadIdx.x & 63, ly = threadIdx.x >> 6;
    int c0 = blockIdx.x * 64, r0 = blockIdx.y * 64;
    #pragma unroll
    for (int i = 0; i < 16; i++)
        t[ly + 4 * i][lx] = in[(size_t)(r0 + ly + 4 * i) * FDIM + c0 + lx];
    __syncthreads();
    #pragma unroll
    for (int i = 0; i < 16; i++)
        out[(size_t)(c0 + ly + 4 * i) * NROW + r0 + lx] = t[lx][ly + 4 * i];
}

__global__ __launch_bounds__(256) void convT_w(const float* __restrict__ Wf,
                                               ushort* __restrict__ WT) {
    __shared__ ushort t[64][65];
    int lx = threadIdx.x & 63, ly = threadIdx.x >> 6;
    int c0 = blockIdx.x * 64, r0 = blockIdx.y * 64;
    #pragma unroll
    for (int i = 0; i < 16; i++)
        t[ly + 4 * i][lx] = f2bf(Wf[(size_t)(r0 + ly + 4 * i) * 512 + c0 + lx]);
    __syncthreads();
    #pragma unroll
    for (int i = 0; i < 16; i++)
        WT[(size_t)(c0 + ly + 4 * i) * 512 + r0 + lx] = t[lx][ly + 4 * i];
}

// ---------------------------------------------------------------------------
// C = A(MxK) * B(NxK)^T, bf16 MFMA 16x16x32, 128x128 tile, 4 waves, BK=64.
// EPI 1: fp32 C + bias[col].  EPI 3: split-K partial (z selects K-chunk 1024).
// EPI 4: bf16 C.
template <int EPI>
__global__ __launch_bounds__(256) void gemm_abT(
    const ushort* __restrict__ A, int lda,
    const ushort* __restrict__ B, int ldb,
    int Kdim, int ldc,
    float* __restrict__ Cf, ushort* __restrict__ Cb,
    const float* __restrict__ bias) {
    constexpr int BK = 64;
    constexpr int NT = 128 * BK;
    constexpr int CPR = BK / 8;               // 8 chunks of 16B per row
    constexpr int PASSES = (128 * CPR) / 256; // 4
    __shared__ __align__(16) ushort smem[2 * NT];
    ushort* As = smem;
    ushort* Bs = smem + NT;

    if constexpr (EPI == 3) {
        A += (size_t)blockIdx.z * 1024;
        B += (size_t)blockIdx.z * 1024;
        Cf += (size_t)blockIdx.z * ((size_t)NROW * 512);
    }

    const int tid = threadIdx.x;
    const int lane = tid & 63, w = tid >> 6;
    const int wr = w >> 1, wc = w & 1;
    const int m0 = blockIdx.y * 128;
    const int n0 = blockIdx.x * 128;

    f32x4 acc[4][4];
    #pragma unroll
    for (int mi = 0; mi < 4; mi++)
        #pragma unroll
        for (int ni = 0; ni < 4; ni++)
            #pragma unroll
            for (int r = 0; r < 4; r++) acc[mi][ni][r] = 0.f;

    for (int k0 = 0; k0 < Kdim; k0 += BK) {
        #pragma unroll
        for (int p = 0; p < PASSES; ++p) {
            int chunk = p * 256 + tid;
            int row = chunk / CPR;
            int kc = chunk % CPR;
            const ushort* asrc = A + (size_t)(m0 + row) * lda + k0 + kc * 8;
            const ushort* bsrc = B + (size_t)(n0 + row) * ldb + k0 + kc * 8;
            ushort* abase = As + (size_t)(p * 256 + w * 64) * 8;
            ushort* bbase = Bs + (size_t)(p * 256 + w * 64) * 8;
            GLL16(asrc, abase);
            GLL16(bsrc, bbase);
        }
        __syncthreads();
        #pragma unroll
        for (int kf = 0; kf < BK / 32; ++kf) {
            const int ko = kf * 32 + (lane >> 4) * 8;
            bf16x8 av[4], bv[4];
            #pragma unroll
            for (int mi = 0; mi < 4; mi++)
                av[mi] = *(const bf16x8*)&As[(wr * 64 + mi * 16 + (lane & 15)) * BK + ko];
            #pragma unroll
            for (int ni = 0; ni < 4; ni++)
                bv[ni] = *(const bf16x8*)&Bs[(wc * 64 + ni * 16 + (lane & 15)) * BK + ko];
            #pragma unroll
            for (int mi = 0; mi < 4; mi++)
                #pragma unroll
                for (int ni = 0; ni < 4; ni++)
                    acc[mi][ni] = __builtin_amdgcn_mfma_f32_16x16x32_bf16(
                        av[mi], bv[ni], acc[mi][ni], 0, 0, 0);
        }
        __syncthreads();
    }

    #pragma unroll
    for (int mi = 0; mi < 4; mi++) {
        #pragma unroll
        for (int ni = 0; ni < 4; ni++) {
            int col = n0 + wc * 64 + ni * 16 + (lane & 15);
            #pragma unroll
            for (int r = 0; r < 4; r++) {
                int rowg = m0 + wr * 64 + mi * 16 + (lane >> 4) * 4 + r;
                size_t off = (size_t)rowg * ldc + col;
                float v = acc[mi][ni][r];
                if constexpr (EPI == 1) {
                    Cf[off] = v + bias[col];
                } else if constexpr (EPI == 3) {
                    Cf[off] = v;
                } else {
                    Cb[off] = f2bf(v);
                }
            }
        }
    }
}

// ---------------------------------------------------------------------------
// topk + build M.  2 waves per row (half = wave&1 owns 2048 cols), 2 rows per
// 256-thread block.  Lane owns 32 cols: j = (qbase+q)*256 + lane*4 + c.
// Per hop: rank v = adj_bf16 * sim_bf16 (self-consistent rounded ranking);
// per-lane top-8 via sorting networks, wave top-8 via 6-level shfl_xor merge
// tree, cross-wave via one LDS exchange (1 barrier/hop).  Retain bits packed.
// macc (fp32) accumulates sum_k a_k^2 * adj * mask;  M = sim * macc  (bf16).
__global__ __launch_bounds__(256) void topk_build_M(
    const ushort* __restrict__ simb, const float* __restrict__ adj,
    const float* __restrict__ rmask, const float* __restrict__ coef,
    ushort* __restrict__ Mout) {
    const int tid = threadIdx.x;
    const int lane = tid & 63;
    const int w = tid >> 6;
    const int rloc = w >> 1;   // row within block
    const int half = w & 1;    // column half
    const int row = blockIdx.x * 2 + rloc;
    const int qbase = half * 8;
    __shared__ float wl[3][2][2][8];

    const int laneoff = lane * 4;

    // sim row: packed bf16, 2 per u32
    const ushort* srow = simb + (size_t)row * NROW;
    uint2 svp[8];
    #pragma unroll
    for (int q = 0; q < 8; q++)
        svp[q] = *(const uint2*)(srow + (qbase + q) * 256 + laneoff);

    float macc[8][4];
    #pragma unroll
    for (int q = 0; q < 8; q++)
        #pragma unroll
        for (int c = 0; c < 4; c++) macc[q][c] = 0.f;

    for (int k = 0; k < 3; ++k) {
        const float* arow = adj + ((size_t)k * NROW + row) * NROW;
        const float* rrow = rmask + ((size_t)k * NROW + row) * NROW;

        uint2 avp[8];
        uint32_t rbits = 0;
        float l[8];

        #pragma unroll
        for (int ch = 0; ch < 4; ch++) {
            float v[8];
            #pragma unroll
            for (int qq = 0; qq < 2; qq++) {
                const int q = ch * 2 + qq;
                f4 a = *(const f4*)(arow + (qbase + q) * 256 + laneoff);
                f4 r = *(const f4*)(rrow + (qbase + q) * 256 + laneoff);
                uint32_t p0 = cvt_pk_bf16(a.x, a.y);
                uint32_t p1 = cvt_pk_bf16(a.z, a.w);
                avp[q].x = p0; avp[q].y = p1;
                rbits |= (r.x < 0.5f ? 1u : 0u) << (q * 4 + 0);
                rbits |= (r.y < 0.5f ? 1u : 0u) << (q * 4 + 1);
                rbits |= (r.z < 0.5f ? 1u : 0u) << (q * 4 + 2);
                rbits |= (r.w < 0.5f ? 1u : 0u) << (q * 4 + 3);
                v[qq * 4 + 0] = up0(p0) * up0(svp[q].x);
                v[qq * 4 + 1] = up1(p0) * up1(svp[q].x);
                v[qq * 4 + 2] = up0(p1) * up0(svp[q].y);
                v[qq * 4 + 3] = up1(p1) * up1(svp[q].y);
            }
            sort8(v);
            if (ch == 0) {
                #pragma unroll
                for (int i = 0; i < 8; i++) l[i] = v[i];
            } else {
                mergeTop8(l, v);
            }
        }

        // wave top-8: 6-level merge tree (all lanes converge to same list)
        #pragma unroll
        for (int lvl = 0; lvl < 6; lvl++) {
            float b[8];
            #pragma unroll
            for (int i = 0; i < 8; i++) b[i] = __shfl_xor(l[i], 1 << lvl);
            mergeTop8(l, b);
        }

        if (lane < 8) wl[k][rloc][half][lane] = l[lane];
        __syncthreads();
        {
            float b[8];
            #pragma unroll
            for (int i = 0; i < 8; i++) b[i] = wl[k][rloc][half ^ 1][i];
            mergeTop8(l, b);
        }
        const float thr = l[7];

        const float ak = coef[k];
        const float aksq = ak * ak;
        #pragma unroll
        for (int q = 0; q < 8; q++) {
            float av0 = up0(avp[q].x), av1 = up1(avp[q].x);
            float av2 = up0(avp[q].y), av3 = up1(avp[q].y);
            float s0 = up0(svp[q].x), s1 = up1(svp[q].x);
            float s2 = up0(svp[q].y), s3 = up1(svp[q].y);
            bool m0 = ((rbits >> (q * 4 + 0)) & 1) || (av0 * s0 >= thr);
            bool m1 = ((rbits >> (q * 4 + 1)) & 1) || (av1 * s1 >= thr);
            bool m2 = ((rbits >> (q * 4 + 2)) & 1) || (av2 * s2 >= thr);
            bool m3 = ((rbits >> (q * 4 + 3)) & 1) || (av3 * s3 >= thr);
            macc[q][0] += m0 ? aksq * av0 : 0.f;
            macc[q][1] += m1 ? aksq * av1 : 0.f;
            macc[q][2] += m2 ? aksq * av2 : 0.f;
            macc[q][3] += m3 ? aksq * av3 : 0.f;
        }
    }

    ushort* mrow = Mout + (size_t)row * NROW;
    #pragma unroll
    for (int q = 0; q < 8; q++) {
        u16x4 o;
        o[0] = f2bf(up0(svp[q].x) * macc[q][0]);
        o[1] = f2bf(up1(svp[q].x) * macc[q][1]);
        o[2] = f2bf(up0(svp[q].y) * macc[q][2]);
        o[3] = f2bf(up1(svp[q].y) * macc[q][3]);
        *(u16x4*)(mrow + (qbase + q) * 256 + laneoff) = o;
    }
}

// ---------------------------------------------------------------------------
// H = relu(cb*Hlow + (1-cb)*sum_z parts[z]) -> bf16
__global__ __launch_bounds__(256) void reduce_relu(
    const float* __restrict__ parts, const float* __restrict__ hlow,
    const float* __restrict__ coef, ushort* __restrict__ Hb) {
    const size_t i = (size_t)blockIdx.x * 256 + threadIdx.x;  // f4 index
    const f4* p4 = (const f4*)parts;
    f4 s = p4[i];
    #pragma unroll
    for (int z = 1; z < 4; z++) s += p4[(size_t)z * 524288 + i];
    f4 hl = ((const f4*)hlow)[i];
    float cb = coef[3];
    u16x4 o;
    #pragma unroll
    for (int c = 0; c < 4; c++) {
        float h = cb * hl[c] + (1.f - cb) * s[c];
        o[c] = f2bf(fmaxf(h, 0.f));
    }
    *((u16x4*)Hb + i) = o;
}

// ---------------------------------------------------------------------------
__global__ __launch_bounds__(256) void logsoftmax_k(const float* __restrict__ L,
                                                    float* __restrict__ out) {
    int row = blockIdx.x, tid = threadIdx.x;
    int lane = tid & 63, w = tid >> 6;
    const float* lr = L + (size_t)row * 512;
    float v0 = lr[tid], v1 = lr[tid + 256];
    __shared__ float bm[4], bs[4];
    float m = fmaxf(v0, v1);
    m = waveReduceMax(m);
    if (lane == 0) bm[w] = m;
    __syncthreads();
    float M = fmaxf(fmaxf(bm[0], bm[1]), fmaxf(bm[2], bm[3]));
    float s = expf(v0 - M) + expf(v1 - M);
    s = waveReduceSum(s);
    if (lane == 0) bs[w] = s;
    __syncthreads();
    float S = bs[0] + bs[1] + bs[2] + bs[3];
    float lse = M + logf(S);
    float* orow = out + (size_t)row * 512;
    orow[tid] = v0 - lse;
    orow[tid + 256] = v1 - lse;
}

// ---------------------------------------------------------------------------
extern "C" void kernel_launch(void* const* d_in, const int* in_sizes, int n_in,
                              void* d_out, int out_size, void* d_ws, size_t ws_size,
                              hipStream_t stream) {
    const float* x     = (const float*)d_in[0];
    const float* adj   = (const float*)d_in[1];
    const float* rmask = (const float*)d_in[2];
    const float* W_in  = (const float*)d_in[3];
    const float* b_in  = (const float*)d_in[4];
    const float* W_out = (const float*)d_in[5];
    const float* b_out = (const float*)d_in[6];
    const float* alpha = (const float*)d_in[7];
    const float* beta  = (const float*)d_in[8];
    float* out = (float*)d_out;

    const size_t MB = 1024 * 1024;
    char* wsb = (char*)d_ws;
    // [0,32):  simb bf16 -> (dead after topk) -> parts fp32 4x8MB -> logits [0,8)
    // [32,64): Mb bf16
    // [64,68): xn bf16    [68,72): xb bf16    [72,76): xbT bf16
    // [76,76.5): WinT     [76.5,77): WoutT
    // [77,85): Hlow fp32  [85,89): Hb bf16    [89): coef
    ushort* simb   = (ushort*)wsb;
    float*  parts  = (float*)wsb;
    float*  logits = (float*)wsb;
    ushort* Mb     = (ushort*)(wsb + 32 * MB);
    ushort* xn     = (ushort*)(wsb + 64 * MB);
    ushort* xb     = (ushort*)(wsb + 68 * MB);
    ushort* xbT    = (ushort*)(wsb + 72 * MB);
    ushort* WinT   = (ushort*)(wsb + 76 * MB);
    ushort* WoutT  = (ushort*)(wsb + 76 * MB + 512 * 1024);
    float*  Hlow   = (float*)(wsb + 77 * MB);
    ushort* Hb     = (ushort*)(wsb + 85 * MB);
    float*  coef   = (float*)(wsb + 89 * MB);

    coef_k<<<1, 64, 0, stream>>>(alpha, beta, coef);
    prep_x<<<NROW, 256, 0, stream>>>(x, xn, xb);
    transpose_xb<<<dim3(8, 64), 256, 0, stream>>>(xb, xbT);
    convT_w<<<dim3(8, 8), 256, 0, stream>>>(W_in, WinT);
    convT_w<<<dim3(8, 8), 256, 0, stream>>>(W_out, WoutT);

    // sim = xn @ xn^T  -> bf16
    gemm_abT<4><<<dim3(32, 32), 256, 0, stream>>>(
        xn, FDIM, xn, FDIM, FDIM, NROW, nullptr, simb, nullptr);

    // combined masked adjacency M (bf16)
    topk_build_M<<<NROW / 2, 256, 0, stream>>>(simb, adj, rmask, coef, Mb);

    // H_low = x @ W_in + b_in
    gemm_abT<1><<<dim3(4, 32), 256, 0, stream>>>(
        xb, FDIM, WinT, FDIM, FDIM, 512, Hlow, nullptr, b_in);

    // split-K=4: parts[z] = M[:, z*1024:+1024] @ x[z*1024:+1024, :]
    gemm_abT<3><<<dim3(4, 32, 4), 256, 0, stream>>>(
        Mb, NROW, xbT, NROW, 1024, 512, parts, nullptr, nullptr);

    // H = relu(b*Hlow + (1-b)*sum parts) -> bf16
    reduce_relu<<<2048, 256, 0, stream>>>(parts, Hlow, coef, Hb);

    // logits = H @ W_out + b_out
    gemm_abT<1><<<dim3(4, 32), 256, 0, stream>>>(
        Hb, 512, WoutT, 512, 512, 512, logits, nullptr, b_out);

    logsoftmax_k<<<NROW, 256, 0, stream>>>(logits, out);
}